// Round 4
// baseline (110.400 us; speedup 1.0000x reference)
//
#include <hip/hip_runtime.h>

// MaskedDenseMatMul: out[b,h,q,k] = (sum_d a[b,h,q,d]*b[b,h,k,d]) * mask[b,0,q,k]
// B=2 H=8 S=2048 D=64, fp32 in/out.  Memory-bound on the 256 MiB output write.
//
// R4 design — contiguous-store epilogue:
//  - cvt pre-pass: A,B fp32->bf16 into d_ws
//  - block = 4 waves; wave owns a 16-row x 256-col output strip (16 MFMA tiles)
//  - MFMA acc (scattered C layout: 16 rows x 64B segments) is bounced through
//    a padded per-wave LDS tile, read back ROW-MAJOR, mask fused, and stored
//    as contiguous 512B-per-half-wave bursts -> HBM page-local write stream
//    (the harness fill kernel proves ~7 TB/s for this pattern)
//  - no __syncthreads: each wave reads only its own LDS region (lgkmcnt order)
//  - plain stores (no nt), full-line writes -> no L2 RMW

typedef __attribute__((ext_vector_type(8))) short bf16x8;
typedef __attribute__((ext_vector_type(4))) float f32x4;

static constexpr int S = 2048;
static constexpr int D = 64;
static constexpr size_t NELEM = (size_t)16 * S * D;  // elems per input
static constexpr int RS = 132;                       // LDS row stride (pad 128+4)

__device__ inline short f2bf(float f) {
    union { float f; unsigned u; } v; v.f = f;
    unsigned r = (v.u + 0x7FFFu + ((v.u >> 16) & 1u)) >> 16;
    return (short)r;
}

// ---------------- conversion pre-pass: both arrays in one launch -------------
__global__ __launch_bounds__(256) void cvt_bf16_kernel(const float* __restrict__ a,
                                                       const float* __restrict__ b,
                                                       short* __restrict__ a16,
                                                       short* __restrict__ b16) {
    const float* src = blockIdx.y ? b : a;
    short* dst       = blockIdx.y ? b16 : a16;
    size_t i = ((size_t)blockIdx.x * 256 + threadIdx.x) * 8;
    f32x4 f0 = *(const f32x4*)(src + i);
    f32x4 f1 = *(const f32x4*)(src + i + 4);
    bf16x8 t;
    t[0] = f2bf(f0[0]); t[1] = f2bf(f0[1]); t[2] = f2bf(f0[2]); t[3] = f2bf(f0[3]);
    t[4] = f2bf(f1[0]); t[5] = f2bf(f1[1]); t[6] = f2bf(f1[2]); t[7] = f2bf(f1[3]);
    *(bf16x8*)(dst + i) = t;
}

// ---------------- main kernel (bf16 inputs from workspace) -------------------
__global__ __launch_bounds__(256) void masked_mm_bf16_kernel(
    const short* __restrict__ A16,
    const short* __restrict__ B16,
    const float* __restrict__ M,
    float* __restrict__ O) {

    __shared__ float lds[4][16][RS];         // 33792 B -> 4 blocks/CU

    const int bh   = blockIdx.z;             // 0..15
    const int bb   = bh >> 3;                // batch
    const int lane = threadIdx.x & 63;
    const int w    = threadIdx.x >> 6;       // wave 0..3

    const int r0 = blockIdx.y * 64 + w * 16; // wave's 16 output rows
    const int c0 = blockIdx.x * 256;         // block's 256 output cols

    const int rlane = lane & 15;             // MFMA operand row within 16
    const int kg    = lane >> 4;             // k-group 0..3

    const short* __restrict__ Ab = A16 + (size_t)bh * S * D;
    const short* __restrict__ Bb = B16 + (size_t)bh * S * D;
    const float* __restrict__ Mb = M + (size_t)bb * S * S;
    float* __restrict__ Ob       = O + (size_t)bh * S * S;

    // A fragments for the wave's 16 rows, K=64 (2 x K=32)
    bf16x8 af0 = *(const bf16x8*)(Ab + (size_t)(r0 + rlane) * D + 0  + kg * 8);
    bf16x8 af1 = *(const bf16x8*)(Ab + (size_t)(r0 + rlane) * D + 32 + kg * 8);

    const int h2  = lane >> 5;   // epilogue: row-half 0/1
    const int c32 = lane & 31;   // epilogue: col/4 within 128-col chunk

#pragma unroll
    for (int ch = 0; ch < 2; ++ch) {
        // ---- compute 8 col-tiles (16 cols each) into the wave's LDS strip ----
#pragma unroll
        for (int t = 0; t < 8; ++t) {
            const int cb = ch * 8 + t;
            const short* pb = Bb + (size_t)(c0 + cb * 16 + rlane) * D + kg * 8;
            bf16x8 b0 = *(const bf16x8*)(pb);
            bf16x8 b1 = *(const bf16x8*)(pb + 32);
            f32x4 z = {0.f, 0.f, 0.f, 0.f};
            // swapped operands: acc[j] = O[r0+rlane][c0+cb*16+kg*4+j]
            z = __builtin_amdgcn_mfma_f32_16x16x32_bf16(b0, af0, z, 0, 0, 0);
            z = __builtin_amdgcn_mfma_f32_16x16x32_bf16(b1, af1, z, 0, 0, 0);
            *(f32x4*)&lds[w][rlane][t * 16 + kg * 4] = z;
        }
        // ---- read back row-major, fuse mask, contiguous stores ----
        // pass p: lanes 0..31 -> row 2p   (512B contiguous),
        //         lanes 32..63 -> row 2p+1 (512B contiguous)
#pragma unroll
        for (int p = 0; p < 8; ++p) {
            const int rr = 2 * p + h2;
            f32x4 v = *(const f32x4*)&lds[w][rr][c32 * 4];
            const size_t gi = (size_t)(r0 + rr) * S + c0 + ch * 128 + c32 * 4;
            f32x4 mkv = *(const f32x4*)(Mb + gi);
            v[0] *= mkv[0]; v[1] *= mkv[1]; v[2] *= mkv[2]; v[3] *= mkv[3];
            *(f32x4*)(Ob + gi) = v;
        }
    }
}

// ---------------- fallback (ws too small): inline conversion -----------------
__global__ __launch_bounds__(256) void masked_mm_f32_kernel(
    const float* __restrict__ A,
    const float* __restrict__ B,
    const float* __restrict__ M,
    float* __restrict__ O) {

    const int bb   = blockIdx.z >> 2;
    const int hp   = blockIdx.z & 3;
    const int lane = threadIdx.x & 63;
    const int w    = threadIdx.x >> 6;
    const int wr = w >> 1, wc = w & 1;
    const int r0 = blockIdx.y * 64 + wr * 32;
    const int c0 = blockIdx.x * 64 + wc * 32;
    const int rlane = lane & 15;
    const int kg    = lane >> 4;

    const float* __restrict__ Mb = M + (size_t)bb * S * S;
    f32x4 mk[2][2];
#pragma unroll
    for (int rb = 0; rb < 2; ++rb)
#pragma unroll
        for (int cb = 0; cb < 2; ++cb)
            mk[rb][cb] = *(const f32x4*)(Mb + (size_t)(r0 + rb * 16 + rlane) * S
                                            + c0 + cb * 16 + kg * 4);

#pragma unroll
    for (int h = 0; h < 2; ++h) {
        const int bh = bb * 8 + hp * 2 + h;
        const float* __restrict__ Ab = A + (size_t)bh * S * D;
        const float* __restrict__ Bb = B + (size_t)bh * S * D;

        bf16x8 af[2][2], bfr[2][2];
#pragma unroll
        for (int rb = 0; rb < 2; ++rb)
#pragma unroll
            for (int kh = 0; kh < 2; ++kh) {
                const float* pa = Ab + (size_t)(r0 + rb * 16 + rlane) * D + kh * 32 + kg * 8;
                f32x4 f0 = *(const f32x4*)pa, f1 = *(const f32x4*)(pa + 4);
                bf16x8 t;
                t[0]=f2bf(f0[0]); t[1]=f2bf(f0[1]); t[2]=f2bf(f0[2]); t[3]=f2bf(f0[3]);
                t[4]=f2bf(f1[0]); t[5]=f2bf(f1[1]); t[6]=f2bf(f1[2]); t[7]=f2bf(f1[3]);
                af[rb][kh] = t;
                const float* pb = Bb + (size_t)(c0 + rb * 16 + rlane) * D + kh * 32 + kg * 8;
                f32x4 g0 = *(const f32x4*)pb, g1 = *(const f32x4*)(pb + 4);
                bf16x8 u;
                u[0]=f2bf(g0[0]); u[1]=f2bf(g0[1]); u[2]=f2bf(g0[2]); u[3]=f2bf(g0[3]);
                u[4]=f2bf(g1[0]); u[5]=f2bf(g1[1]); u[6]=f2bf(g1[2]); u[7]=f2bf(g1[3]);
                bfr[rb][kh] = u;
            }

        f32x4 acc[2][2];
#pragma unroll
        for (int rb = 0; rb < 2; ++rb)
#pragma unroll
            for (int cb = 0; cb < 2; ++cb) {
                f32x4 z = {0.f, 0.f, 0.f, 0.f};
                z = __builtin_amdgcn_mfma_f32_16x16x32_bf16(bfr[cb][0], af[rb][0], z, 0, 0, 0);
                z = __builtin_amdgcn_mfma_f32_16x16x32_bf16(bfr[cb][1], af[rb][1], z, 0, 0, 0);
                acc[rb][cb] = z;
            }

        float* __restrict__ Ob = O + (size_t)bh * S * S;
#pragma unroll
        for (int rb = 0; rb < 2; ++rb)
#pragma unroll
            for (int cb = 0; cb < 2; ++cb) {
                f32x4 v;
                v[0] = acc[rb][cb][0] * mk[rb][cb][0];
                v[1] = acc[rb][cb][1] * mk[rb][cb][1];
                v[2] = acc[rb][cb][2] * mk[rb][cb][2];
                v[3] = acc[rb][cb][3] * mk[rb][cb][3];
                *(f32x4*)(Ob + (size_t)(r0 + rb * 16 + rlane) * S
                             + c0 + cb * 16 + kg * 4) = v;
            }
    }
}

extern "C" void kernel_launch(void* const* d_in, const int* in_sizes, int n_in,
                              void* d_out, int out_size, void* d_ws, size_t ws_size,
                              hipStream_t stream) {
    const float* a = (const float*)d_in[0];
    const float* b = (const float*)d_in[1];
    const float* m = (const float*)d_in[2];
    float* o = (float*)d_out;

    dim3 block(256);

    const size_t ws_need = 2 * NELEM * sizeof(short);  // 8.4 MB
    if (ws_size >= ws_need) {
        short* a16 = (short*)d_ws;
        short* b16 = a16 + NELEM;
        const int cvt_blocks = (int)(NELEM / (256 * 8));  // 1024
        hipLaunchKernelGGL(cvt_bf16_kernel, dim3(cvt_blocks, 2), block, 0, stream,
                           a, b, a16, b16);
        dim3 grid(S / 256, S / 64, 16);  // (col panels, row panels, b*h)
        hipLaunchKernelGGL(masked_mm_bf16_kernel, grid, block, 0, stream, a16, b16, m, o);
    } else {
        dim3 grid(S / 64, S / 64, 8);
        hipLaunchKernelGGL(masked_mm_f32_kernel, grid, block, 0, stream, a, b, m, o);
    }
}